// Round 6
// baseline (201.245 us; speedup 1.0000x reference)
//
#include <hip/hip_runtime.h>
#include <hip/hip_bf16.h>

#define NREV 500000
#define DIM  128
#define KDIM 384

typedef __attribute__((ext_vector_type(4))) float f32x4;
typedef __attribute__((ext_vector_type(8))) short bf16x8;

__device__ __forceinline__ unsigned short f2bf_s(float x) {
    // round-to-nearest-even f32 -> bf16
    unsigned int u = __builtin_bit_cast(unsigned int, x);
    u = (u + 0x7FFFu + ((u >> 16) & 1u)) >> 16;
    return (unsigned short)u;
}

// W [384][128] f32 -> Bw frag-linear bf16:
// Bw[((KS*8+fg)*64 + l)*8 + j] = bf16( W[KS*32 + (l>>4)*8 + j][fg*16 + (l&15)] )
// so each lane's 16B B-fragment is one contiguous dwordx4 (L2-resident, 96KB).
__global__ void wconv_kernel(const float* __restrict__ W,
                             unsigned short* __restrict__ Bw) {
    int e = blockIdx.x * 256 + threadIdx.x;
    if (e < 12 * 8 * 64 * 8) {
        int j  = e & 7;
        int l  = (e >> 3) & 63;
        int fg = (e >> 9) & 7;
        int ks = e >> 12;
        int n = fg * 16 + (l & 15);
        int k = ks * 32 + ((l >> 4) << 3) + j;
        Bw[e] = f2bf_s(W[k * DIM + n]);
    }
}

__device__ __forceinline__ void gload_lds16(const void* g, void* l) {
    __builtin_amdgcn_global_load_lds(
        (const __attribute__((address_space(1))) void*)g,
        (__attribute__((address_space(3))) void*)l, 16, 0, 0);
}

// pack hi16 of two f32 into one dword of two bf16 (truncation; absmax 0.031
// vs threshold 0.109): single v_perm_b32
__device__ __forceinline__ unsigned int pk2(float lo, float hi) {
    return __builtin_amdgcn_perm(__builtin_bit_cast(unsigned int, hi),
                                 __builtin_bit_cast(unsigned int, lo),
                                 0x07060302u);
}
__device__ __forceinline__ bf16x8 cvt8(f32x4 a, f32x4 b) {
    union { bf16x8 v; unsigned int u[4]; } U;
    U.u[0] = pk2(a[0], a[1]);
    U.u[1] = pk2(a[2], a[3]);
    U.u[2] = pk2(b[0], b[1]);
    U.u[3] = pk2(b[2], b[3]);
    return U.v;
}

// Fused gather + GEMM + ReLU, phase-tiled.
// Block: 64 rows x 128 cols, 4 waves (wave-tile 32x64). 3 phases (review/
// user/item), each consuming K=128 from a full-row LDS tile.
// KEY CHANGE vs R5: each gathered row's 512B is fetched CONTIGUOUSLY by one
// global_load_lds instruction (2 rows/inst, lanes 0-31 / 32-63), instead of
// 4x128B pieces spread over ~10us -> DRAM sees 512B bursts. Sync points
// drop 12 -> 3 (one vmcnt(0)+barrier per phase, ~10us of issued-ahead work).
// LDS slot layout: sigma = R*32 + (c ^ (R&7)) (c = 16B granule index in row)
// -> DMA dest lane-linear, ds_read_b128 <=2-way conflicted.
__global__ __launch_bounds__(256, 2) void agg_kernel(
    const float* __restrict__ rev,
    const float* __restrict__ item,
    const float* __restrict__ user,
    const int*   __restrict__ uidx,
    const int*   __restrict__ iidx,
    const unsigned short* __restrict__ Bw,
    float* __restrict__ out)
{
    __shared__ __align__(16) float Atile[2][64 * 128];   // 2 x 32KB

    const int r0   = blockIdx.x * 64;
    const int t    = threadIdx.x;
    const int w    = t >> 6, lane = t & 63;
    const int wr   = w >> 1, wc = w & 1;
    const int lm   = lane & 15, lk = lane >> 4;
    const int h    = lane >> 5;          // which of the 2 rows per DMA inst
    const int l31  = lane & 31;

    // ---- preload gather indices: wave w stages rows 16w..16w+15;
    // per round r (0..7) this lane handles row R = 16w + 2r + h.
    int rrow[8], urow[8], irow[8];
    #pragma unroll
    for (int r = 0; r < 8; ++r) {
        int gr = r0 + 16 * w + 2 * r + h;
        if (gr >= NREV) gr = NREV - 1;    // clamp tail; stores predicated
        rrow[r] = gr;
        urow[r] = uidx[gr];
        irow[r] = iidx[gr];
    }

    // issue 8 DMA insts staging the 64x512B A-tile for phase p into buf.
    // lane's source granule: cs = l31 ^ (R&7); R&7 = (2r+h)&7.
    // LDS dest: (16w+2r)*512 + lane*16  (lane-linear per inst).
    auto prefetchA = [&](int p, int buf) {
        #pragma unroll
        for (int r = 0; r < 8; ++r) {
            int row = (p == 0) ? rrow[r] : (p == 1) ? urow[r] : irow[r];
            const float* tab = (p == 0) ? rev : (p == 1) ? user : item;
            const int cs = (l31 ^ ((2 * r + h) & 7)) << 4;   // byte in row
            gload_lds16((const char*)(tab + (size_t)row * DIM) + cs,
                        (char*)&Atile[buf][0] + (16 * w + 2 * r) * 512 + lane * 16);
        }
    };

    f32x4 acc[2][4];
    #pragma unroll
    for (int i = 0; i < 2; ++i)
        #pragma unroll
        for (int j = 0; j < 4; ++j)
            acc[i][j] = (f32x4){0.f, 0.f, 0.f, 0.f};

    const unsigned short* bbase = Bw + ((wc * 4) * 64 + lane) * 8;

    prefetchA(0, 0);

    #pragma unroll
    for (int p = 0; p < 3; ++p) {
        asm volatile("s_waitcnt vmcnt(0)" ::: "memory");  // A(p) landed
        __builtin_amdgcn_s_barrier();                     // all waves' pieces in
        if (p < 2) prefetchA(p + 1, (p + 1) & 1);         // next phase in flight

        // B fragments for phase p, register-direct from L2-resident Bw.
        // Compiler's wait for these counts the 8 A-gloads above -> vmcnt(8),
        // keeping the prefetch in flight.
        bf16x8 breg[4][4];
        #pragma unroll
        for (int ks = 0; ks < 4; ++ks)
            #pragma unroll
            for (int nf = 0; nf < 4; ++nf)
                breg[ks][nf] = *reinterpret_cast<const bf16x8*>(
                    bbase + (size_t)(((p * 4 + ks) * 8 + nf)) * 512);

        const char* la = (const char*)&Atile[p & 1][0];
        #pragma unroll
        for (int ks = 0; ks < 4; ++ks) {
            #pragma unroll
            for (int mf = 0; mf < 2; ++mf) {
                const int R  = wr * 32 + mf * 16 + lm;
                const int c0 = ks * 8 + lk * 2;
                const int s0 = R * 32 + (c0 ^ (R & 7));
                const int s1 = R * 32 + ((c0 + 1) ^ (R & 7));
                f32x4 f0 = *reinterpret_cast<const f32x4*>(la + s0 * 16);
                f32x4 f1 = *reinterpret_cast<const f32x4*>(la + s1 * 16);
                bf16x8 af = cvt8(f0, f1);
                #pragma unroll
                for (int nf = 0; nf < 4; ++nf)
                    acc[mf][nf] = __builtin_amdgcn_mfma_f32_16x16x32_bf16(
                        af, breg[ks][nf], acc[mf][nf], 0, 0, 0);
            }
        }
    }

    // ---- epilogue: ReLU + f32 store (C/D: col=lane&15, row=(lane>>4)*4+j)
    #pragma unroll
    for (int mf = 0; mf < 2; ++mf) {
        #pragma unroll
        for (int j = 0; j < 4; ++j) {
            int row = r0 + wr * 32 + mf * 16 + lk * 4 + j;
            if (row < NREV) {
                float* orow = out + (size_t)row * DIM + wc * 64;
                #pragma unroll
                for (int nf = 0; nf < 4; ++nf)
                    orow[nf * 16 + lm] = fmaxf(acc[mf][nf][j], 0.0f);
            }
        }
    }
}

extern "C" void kernel_launch(void* const* d_in, const int* in_sizes, int n_in,
                              void* d_out, int out_size, void* d_ws, size_t ws_size,
                              hipStream_t stream) {
    const float* rev  = (const float*)d_in[0];
    const float* item = (const float*)d_in[1];
    const float* user = (const float*)d_in[2];
    const int*   uidx = (const int*)d_in[3];
    const int*   iidx = (const int*)d_in[4];
    const float* W    = (const float*)d_in[5];
    unsigned short* Bw = (unsigned short*)d_ws;   // 12*8*64*8*2 = 98304 B
    float* out = (float*)d_out;

    wconv_kernel<<<192, 256, 0, stream>>>(W, Bw);

    int nblocks = (NREV + 63) / 64;   // 7813
    agg_kernel<<<nblocks, 256, 0, stream>>>(rev, item, user, uidx, iidx, Bw, out);
}